// Round 1
// baseline (261.594 us; speedup 1.0000x reference)
//
#include <hip/hip_runtime.h>
#include <hip/hip_bf16.h>

// attentionHead: out = ((x@Wqkv+b) -> Q,K,V; (QK^T)V ; @Wout + b_out)
// Key identity (no softmax!): (QK^T)V = Q(K^T V). Per-head M_h = K^T V is 64x64.
// Then out = Q_cat @ (blockdiag(M_h) @ Wout) + b_out, where Q_cat = QKV[:, :768].
//
// Kernels:
//  1. transpose_cvt: Wqkv -> WqkvT bf16, Wout -> WoutT bf16
//  2. gemm<A_F32=1>: QKV[16384,2304] bf16 = x @ Wqkv + b_qkv
//  3. ktv: M_h[64,64] bf16 = K^T V per (b,h)   (VALU, 1.6 GFLOP)
//  4. gemm: W2T[b][j][h*64+d] = sum_e WoutT[j][h*64+e] * M_h[d][e]
//  5. gemm: out f32 = Q @ W2[b] + b_out  (written straight to d_out)

typedef __attribute__((ext_vector_type(8))) short bf16x8;
typedef __attribute__((ext_vector_type(4))) short short4v;
typedef __attribute__((ext_vector_type(4))) float f32x4;
typedef __attribute__((ext_vector_type(4))) float float4v;

__device__ __forceinline__ unsigned short f2bf(float f) {
  union { float f; unsigned int u; } v; v.f = f;
  unsigned int u = v.u;
  return (unsigned short)((u + 0x7FFFu + ((u >> 16) & 1u)) >> 16);  // RNE
}
__device__ __forceinline__ float bf2f(unsigned short s) {
  union { unsigned int u; float f; } v; v.u = ((unsigned int)s) << 16;
  return v.f;
}

// ---------------- transpose + convert f32 -> bf16 --------------------------
// out[c][r] = bf16(in[r][c]); R, C multiples of 32.
__global__ __launch_bounds__(256) void transpose_cvt(const float* __restrict__ in,
                                                     unsigned short* __restrict__ out,
                                                     int R, int C) {
  __shared__ unsigned short tile[32][33];
  const int bx = blockIdx.x * 32;  // col base
  const int by = blockIdx.y * 32;  // row base
  const int tx = threadIdx.x & 31, ty = threadIdx.x >> 5;  // ty in 0..7
  #pragma unroll
  for (int i = 0; i < 32; i += 8)
    tile[ty + i][tx] = f2bf(in[(long long)(by + ty + i) * C + bx + tx]);
  __syncthreads();
  #pragma unroll
  for (int i = 0; i < 32; i += 8)
    out[(long long)(bx + ty + i) * R + by + tx] = tile[tx][ty + i];
}

// ---------------- generic batched MFMA GEMM --------------------------------
// D[m][n] = sum_k A[m][k] * BT[n][k]  (+ bias[n])
// A: f32 or bf16 row-major [M,K]; BT: bf16 [N,K]; C: bf16 or f32 [M,N] (ldc).
// Batch z: (q,r) = (z/divz, z%divz); per-operand offset = q*s1 + r*s2 (elements).
// Requires: M % 128 == 0, K % 64 == 0, lda/ldbt % 8 == 0. N guarded.
struct GemmArgs {
  const void* A;
  const unsigned short* BT;
  void* C;
  const float* bias;
  int M, N, K;
  int lda, ldbt, ldc;
  int divz;
  long long sA1, sA2, sB1, sB2, sC1, sC2;
};

template <bool A_F32, bool OUT_F32, bool BIAS>
__global__ __launch_bounds__(256) void gemm_kernel(GemmArgs g) {
  constexpr int LDT = 72;  // 64 + 8 pad (144B row: 8 distinct bank-starts -> ~2-way)
  __shared__ unsigned short As[128 * LDT];
  __shared__ unsigned short Bs[128 * LDT];

  const int z = blockIdx.z;
  const int q = z / g.divz, r = z % g.divz;
  const long long offA = q * g.sA1 + r * g.sA2;
  const long long offB = q * g.sB1 + r * g.sB2;
  const long long offC = q * g.sC1 + r * g.sC2;
  const int bn = blockIdx.x * 128;
  const int bm = blockIdx.y * 128;
  const int tid = threadIdx.x;
  const int lane = tid & 63;
  const int wave = tid >> 6;
  const int wr = (wave >> 1) * 64, wc = (wave & 1) * 64;  // 2x2 waves, 64x64 each
  const int l15 = lane & 15, l4 = lane >> 4;

  const f32x4 fz = {0.f, 0.f, 0.f, 0.f};
  f32x4 acc[4][4];
  #pragma unroll
  for (int i = 0; i < 4; ++i)
    #pragma unroll
    for (int j = 0; j < 4; ++j) acc[i][j] = fz;

  const int srow = tid >> 3;       // 0..31 (row within sweep)
  const int scg = (tid & 7) * 8;   // k-chunk start (elements)

  for (int kt = 0; kt < g.K; kt += 64) {
    __syncthreads();
    // ---- stage A tile [128][64] and B tile [128 n][64 k] ----
    #pragma unroll
    for (int s = 0; s < 4; ++s) {
      const int row = s * 32 + srow;
      bf16x8 av;
      if (A_F32) {
        const float* ap = (const float*)g.A + offA + (long long)(bm + row) * g.lda + kt + scg;
        float4v v0 = *(const float4v*)ap;
        float4v v1 = *(const float4v*)(ap + 4);
        av[0] = (short)f2bf(v0[0]); av[1] = (short)f2bf(v0[1]);
        av[2] = (short)f2bf(v0[2]); av[3] = (short)f2bf(v0[3]);
        av[4] = (short)f2bf(v1[0]); av[5] = (short)f2bf(v1[1]);
        av[6] = (short)f2bf(v1[2]); av[7] = (short)f2bf(v1[3]);
      } else {
        av = *(const bf16x8*)((const unsigned short*)g.A + offA +
                              (long long)(bm + row) * g.lda + kt + scg);
      }
      *(bf16x8*)&As[row * LDT + scg] = av;

      bf16x8 bv = {0, 0, 0, 0, 0, 0, 0, 0};
      if (bn + row < g.N)
        bv = *(const bf16x8*)(g.BT + offB + (long long)(bn + row) * g.ldbt + kt + scg);
      *(bf16x8*)&Bs[row * LDT + scg] = bv;
    }
    __syncthreads();

    // ---- 2 k-steps of 32, 16 MFMA each ----
    #pragma unroll
    for (int ks = 0; ks < 64; ks += 32) {
      const int kk = ks + l4 * 8;
      bf16x8 af[4], bfv[4];
      #pragma unroll
      for (int i = 0; i < 4; ++i) {
        af[i]  = *(const bf16x8*)&As[(wr + i * 16 + l15) * LDT + kk];
        bfv[i] = *(const bf16x8*)&Bs[(wc + i * 16 + l15) * LDT + kk];
      }
      #pragma unroll
      for (int mi = 0; mi < 4; ++mi)
        #pragma unroll
        for (int ni = 0; ni < 4; ++ni)
          acc[mi][ni] =
              __builtin_amdgcn_mfma_f32_16x16x32_bf16(af[mi], bfv[ni], acc[mi][ni], 0, 0, 0);
    }
  }

  // ---- epilogue: C/D layout col=lane&15, row=(lane>>4)*4+i ----
  #pragma unroll
  for (int mi = 0; mi < 4; ++mi) {
    #pragma unroll
    for (int ni = 0; ni < 4; ++ni) {
      #pragma unroll
      for (int i = 0; i < 4; ++i) {
        const int row = bm + wr + mi * 16 + l4 * 4 + i;
        const int col = bn + wc + ni * 16 + l15;
        if (row < g.M && col < g.N) {
          float v = acc[mi][ni][i];
          if (BIAS) v += g.bias[col];
          if (OUT_F32)
            ((float*)g.C)[offC + (long long)row * g.ldc + col] = v;
          else
            ((unsigned short*)g.C)[offC + (long long)row * g.ldc + col] = f2bf(v);
        }
      }
    }
  }
}

// ---------------- K^T V per head (VALU) ------------------------------------
// M_h[d][e] = sum_t K[t,d] * V[t,e]; K[t,d] = QKV[(b*1024+t)*2304 + 768 + h*64 + d]
__global__ __launch_bounds__(256) void ktv_kernel(const unsigned short* __restrict__ QKV,
                                                  unsigned short* __restrict__ Mh) {
  const int z = blockIdx.x;  // b*12 + h
  const int b = z / 12, h = z % 12;
  __shared__ unsigned short Ks[32 * 64];
  __shared__ unsigned short Vs[32 * 64];
  const int tid = threadIdx.x;
  const int ti = tid & 15, tj = tid >> 4;  // d0 = 4*ti, e0 = 4*tj
  const int srow = tid >> 3, scg = (tid & 7) * 8;

  float acc[4][4];
  #pragma unroll
  for (int i = 0; i < 4; ++i)
    #pragma unroll
    for (int j = 0; j < 4; ++j) acc[i][j] = 0.f;

  const long long baseK = (long long)b * 1024 * 2304 + 768 + h * 64;
  for (int tc = 0; tc < 1024; tc += 32) {
    __syncthreads();
    const long long gidx = baseK + (long long)(tc + srow) * 2304 + scg;
    *(bf16x8*)&Ks[srow * 64 + scg] = *(const bf16x8*)&QKV[gidx];
    *(bf16x8*)&Vs[srow * 64 + scg] = *(const bf16x8*)&QKV[gidx + 768];
    __syncthreads();
    #pragma unroll 8
    for (int t = 0; t < 32; ++t) {
      const short4v ka = *(const short4v*)&Ks[t * 64 + ti * 4];
      const short4v va = *(const short4v*)&Vs[t * 64 + tj * 4];
      float a0 = bf2f((unsigned short)ka[0]), a1 = bf2f((unsigned short)ka[1]);
      float a2 = bf2f((unsigned short)ka[2]), a3 = bf2f((unsigned short)ka[3]);
      float b0 = bf2f((unsigned short)va[0]), b1 = bf2f((unsigned short)va[1]);
      float b2 = bf2f((unsigned short)va[2]), b3 = bf2f((unsigned short)va[3]);
      acc[0][0] += a0 * b0; acc[0][1] += a0 * b1; acc[0][2] += a0 * b2; acc[0][3] += a0 * b3;
      acc[1][0] += a1 * b0; acc[1][1] += a1 * b1; acc[1][2] += a1 * b2; acc[1][3] += a1 * b3;
      acc[2][0] += a2 * b0; acc[2][1] += a2 * b1; acc[2][2] += a2 * b2; acc[2][3] += a2 * b3;
      acc[3][0] += a3 * b0; acc[3][1] += a3 * b1; acc[3][2] += a3 * b2; acc[3][3] += a3 * b3;
    }
  }
  const long long mb = (long long)z * 4096;
  #pragma unroll
  for (int i = 0; i < 4; ++i) {
    short4v mv;
    #pragma unroll
    for (int j = 0; j < 4; ++j) mv[j] = (short)f2bf(acc[i][j]);
    *(short4v*)&Mh[mb + (ti * 4 + i) * 64 + tj * 4] = mv;
  }
}

// ---------------------------------------------------------------------------
extern "C" void kernel_launch(void* const* d_in, const int* in_sizes, int n_in,
                              void* d_out, int out_size, void* d_ws, size_t ws_size,
                              hipStream_t stream) {
  (void)in_sizes; (void)n_in; (void)out_size; (void)ws_size;
  const float* x    = (const float*)d_in[0];  // [16384,768]
  const float* Wqkv = (const float*)d_in[1];  // [768,2304]
  const float* bqkv = (const float*)d_in[2];  // [2304]
  const float* Wout = (const float*)d_in[3];  // [768,768]
  const float* bout = (const float*)d_in[4];  // [768]
  float* out = (float*)d_out;                 // [16384,768] f32

  char* ws = (char*)d_ws;
  size_t off = 0;
  auto carve = [&](size_t bytes) {
    char* p = ws + off;
    off += (bytes + 255) & ~(size_t)255;
    return p;
  };
  unsigned short* WqkvT = (unsigned short*)carve((size_t)2304 * 768 * 2);   // [2304][768]
  unsigned short* WoutT = (unsigned short*)carve((size_t)768 * 768 * 2);    // [768][768] (W_out^T)
  unsigned short* QKV   = (unsigned short*)carve((size_t)16384 * 2304 * 2); // [16384][2304]
  unsigned short* Mh    = (unsigned short*)carve((size_t)192 * 64 * 64 * 2);// [192][64 d][64 e]
  unsigned short* W2T   = (unsigned short*)carve((size_t)16 * 768 * 768 * 2);// [16][768 j][768 col]
  // total ~100.8 MB of d_ws

  transpose_cvt<<<dim3(2304 / 32, 768 / 32), 256, 0, stream>>>(Wqkv, WqkvT, 768, 2304);
  transpose_cvt<<<dim3(768 / 32, 768 / 32), 256, 0, stream>>>(Wout, WoutT, 768, 768);

  // 1) QKV = x @ Wqkv + b_qkv   (A f32 -> bf16 on the fly)
  GemmArgs g1{};
  g1.A = x; g1.BT = WqkvT; g1.C = QKV; g1.bias = bqkv;
  g1.M = 16384; g1.N = 2304; g1.K = 768;
  g1.lda = 768; g1.ldbt = 768; g1.ldc = 2304;
  g1.divz = 1;
  gemm_kernel<true, false, true><<<dim3(18, 128, 1), 256, 0, stream>>>(g1);

  // 2) M_h = K^T V per (b,h)
  ktv_kernel<<<dim3(192), 256, 0, stream>>>(QKV, Mh);

  // 3) W2T[b][j][h*64+d] = sum_e WoutT[j][h*64+e] * Mh[(b,h)][d][e]
  //    GEMM: A = WoutT (+h*64 col offset), BT = Mh, C = W2T (+ b,h offsets)
  GemmArgs g2{};
  g2.A = WoutT; g2.BT = Mh; g2.C = W2T; g2.bias = nullptr;
  g2.M = 768; g2.N = 64; g2.K = 64;
  g2.lda = 768; g2.ldbt = 64; g2.ldc = 768;
  g2.divz = 12;
  g2.sA1 = 0;        g2.sA2 = 64;
  g2.sB1 = 12 * 4096; g2.sB2 = 4096;
  g2.sC1 = 589824;    g2.sC2 = 64;
  gemm_kernel<false, false, false><<<dim3(1, 6, 192), 256, 0, stream>>>(g2);

  // 4) out[b] = Q[b] @ W2[b] + b_out   (Q = QKV cols 0..767, lda=2304), f32 out
  GemmArgs g3{};
  g3.A = QKV; g3.BT = W2T; g3.C = out; g3.bias = bout;
  g3.M = 1024; g3.N = 768; g3.K = 768;
  g3.lda = 2304; g3.ldbt = 768; g3.ldc = 768;
  g3.divz = 1;
  g3.sA1 = 2359296;  // 1024*2304
  g3.sB1 = 589824;   // 768*768
  g3.sC1 = 786432;   // 1024*768
  gemm_kernel<false, true, true><<<dim3(6, 8, 16), 256, 0, stream>>>(g3);
}

// Round 2
// 244.731 us; speedup vs baseline: 1.0689x; 1.0689x over previous
//
#include <hip/hip_runtime.h>
#include <hip/hip_bf16.h>

// attentionHead: out = ((x@Wqkv+b) -> Q,K,V; (QK^T)V ; @Wout + b_out)
// No softmax => (QK^T)V = Q(K^T V). Per-head M_h = K^T V is 64x64.
// out = Q_cat @ (blockdiag(M_h) @ Wout) + b_out, Q_cat = QKV[:, :768].
//
// Pipeline:
//  0. cvt:          xbf  = bf16(x)                       [16384,768]
//  1. transpose_cvt: WqkvT, WoutT (bf16, transposed)
//  2. gemm_lds:     QKV  = xbf @ Wqkv + b_qkv  (bf16)    [16384,2304]  m97-structure
//  3. ktv:          M_h  = K^T V per (b,h)     (bf16)    [192,64,64]
//  4. gemm_pad:     W2T[b][j][:] = blockdiag(Mh) @ Wout  (bf16, transposed)
//  5. gemm_lds:     out  = Q @ W2[b] + b_out   (f32)     [16,1024,768]

typedef __attribute__((ext_vector_type(8))) short bf16x8;
typedef __attribute__((ext_vector_type(4))) short short4v;
typedef __attribute__((ext_vector_type(4))) float f32x4;
typedef __attribute__((ext_vector_type(4))) float float4v;

typedef __attribute__((address_space(1))) const unsigned char ga_u8;
typedef __attribute__((address_space(3))) unsigned char la_u8;

__device__ __forceinline__ unsigned short f2bf(float f) {
  union { float f; unsigned int u; } v; v.f = f;
  unsigned int u = v.u;
  return (unsigned short)((u + 0x7FFFu + ((u >> 16) & 1u)) >> 16);  // RNE
}
__device__ __forceinline__ float bf2f(unsigned short s) {
  union { unsigned int u; float f; } v; v.u = ((unsigned int)s) << 16;
  return v.f;
}

// ---------------- f32 -> bf16 bulk convert ---------------------------------
// n8 = n/8 chunks; each thread converts 8 elems.
__global__ __launch_bounds__(256) void cvt_f32_bf16(const float* __restrict__ in,
                                                    unsigned short* __restrict__ out) {
  const long long i = (long long)(blockIdx.x * 256 + threadIdx.x) * 8;
  float4v v0 = *(const float4v*)(in + i);
  float4v v1 = *(const float4v*)(in + i + 4);
  bf16x8 o;
  o[0] = (short)f2bf(v0[0]); o[1] = (short)f2bf(v0[1]);
  o[2] = (short)f2bf(v0[2]); o[3] = (short)f2bf(v0[3]);
  o[4] = (short)f2bf(v1[0]); o[5] = (short)f2bf(v1[1]);
  o[6] = (short)f2bf(v1[2]); o[7] = (short)f2bf(v1[3]);
  *(bf16x8*)(out + i) = o;
}

// ---------------- transpose + convert f32 -> bf16 --------------------------
__global__ __launch_bounds__(256) void transpose_cvt(const float* __restrict__ in,
                                                     unsigned short* __restrict__ out,
                                                     int R, int C) {
  __shared__ unsigned short tile[32][33];
  const int bx = blockIdx.x * 32;
  const int by = blockIdx.y * 32;
  const int tx = threadIdx.x & 31, ty = threadIdx.x >> 5;
  #pragma unroll
  for (int i = 0; i < 32; i += 8)
    tile[ty + i][tx] = f2bf(in[(long long)(by + ty + i) * C + bx + tx]);
  __syncthreads();
  #pragma unroll
  for (int i = 0; i < 32; i += 8)
    out[(long long)(bx + ty + i) * R + by + tx] = tile[tx][ty + i];
}

// ---------------- shared GEMM args -----------------------------------------
// D[m][n] = sum_k A[m][k] * BT[n][k]  (+ bias[n])
struct GemmArgs {
  const void* A;
  const unsigned short* BT;
  void* C;
  const float* bias;
  int M, N, K;
  int lda, ldbt, ldc;
  int divz;
  long long sA1, sA2, sB1, sB2, sC1, sC2;
};

// ---------------- m97-structure GEMM: global_load_lds, linear LDS ----------
// Requires: M%128==0, N%128==0, K%64==0, lda/ldbt %8==0, (gridDim.x*gridDim.y)%8==0.
template <bool OUT_F32, bool BIAS>
__global__ __launch_bounds__(256) void gemm_lds(GemmArgs g) {
  __shared__ unsigned short As[128 * 64];
  __shared__ unsigned short Bs[128 * 64];

  // bijective XCD swizzle over linearized (x,y)
  const int nwg = gridDim.x * gridDim.y;
  const int wg = blockIdx.y * gridDim.x + blockIdx.x;
  const int cpx = nwg >> 3;
  const int swz = (wg & 7) * cpx + (wg >> 3);
  const int bx = swz % gridDim.x, by = swz / gridDim.x;

  const int z = blockIdx.z;
  const int q = z / g.divz, r = z % g.divz;
  const long long offA = q * g.sA1 + r * g.sA2;
  const long long offB = q * g.sB1 + r * g.sB2;
  const long long offC = q * g.sC1 + r * g.sC2;
  const int bn = bx * 128;
  const int bm = by * 128;
  const int tid = threadIdx.x;
  const int lane = tid & 63;
  const int wave = tid >> 6;
  const int wr = (wave >> 1) * 64, wc = (wave & 1) * 64;
  const int l15 = lane & 15, l4 = lane >> 4;

  const f32x4 fz = {0.f, 0.f, 0.f, 0.f};
  f32x4 acc[4][4];
  #pragma unroll
  for (int i = 0; i < 4; ++i)
    #pragma unroll
    for (int j = 0; j < 4; ++j) acc[i][j] = fz;

  const unsigned short* Abase = (const unsigned short*)g.A + offA;
  const unsigned short* Bbase = g.BT + offB;

  for (int kt = 0; kt < g.K; kt += 64) {
    // stage A and B tiles [128][64] via async global->LDS, 16B/lane
    #pragma unroll
    for (int s = 0; s < 4; ++s) {
      const int ci = s * 256 + tid;      // chunk 0..1023 (16B each)
      const int row = ci >> 3;
      const int cc = (ci & 7) << 3;
      const unsigned short* gaA = Abase + (long long)(bm + row) * g.lda + kt + cc;
      __builtin_amdgcn_global_load_lds((ga_u8*)gaA, (la_u8*)&As[ci << 3], 16, 0, 0);
      const unsigned short* gaB = Bbase + (long long)(bn + row) * g.ldbt + kt + cc;
      __builtin_amdgcn_global_load_lds((ga_u8*)gaB, (la_u8*)&Bs[ci << 3], 16, 0, 0);
    }
    __syncthreads();  // drains vmcnt -> tiles ready

    #pragma unroll
    for (int ks = 0; ks < 64; ks += 32) {
      const int kk = ks + l4 * 8;
      bf16x8 af[4], bfv[4];
      #pragma unroll
      for (int i = 0; i < 4; ++i) {
        af[i]  = *(const bf16x8*)&As[(wr + i * 16 + l15) * 64 + kk];
        bfv[i] = *(const bf16x8*)&Bs[(wc + i * 16 + l15) * 64 + kk];
      }
      #pragma unroll
      for (int mi = 0; mi < 4; ++mi)
        #pragma unroll
        for (int ni = 0; ni < 4; ++ni)
          acc[mi][ni] =
              __builtin_amdgcn_mfma_f32_16x16x32_bf16(af[mi], bfv[ni], acc[mi][ni], 0, 0, 0);
    }
    __syncthreads();  // all reads done before next stage overwrites
  }

  // epilogue: C/D layout col=lane&15, row=(lane>>4)*4+i
  #pragma unroll
  for (int mi = 0; mi < 4; ++mi) {
    #pragma unroll
    for (int ni = 0; ni < 4; ++ni) {
      #pragma unroll
      for (int i = 0; i < 4; ++i) {
        const int row = bm + wr + mi * 16 + l4 * 4 + i;
        const int col = bn + wc + ni * 16 + l15;
        float v = acc[mi][ni][i];
        if (BIAS) v += g.bias[col];
        if (OUT_F32)
          ((float*)g.C)[offC + (long long)row * g.ldc + col] = v;
        else
          ((unsigned short*)g.C)[offC + (long long)row * g.ldc + col] = f2bf(v);
      }
    }
  }
}

// ---------------- padded reg-staging GEMM (for small/guarded shapes) -------
// Requires: M%128==0, K%64==0. N guarded.
template <bool OUT_F32, bool BIAS>
__global__ __launch_bounds__(256) void gemm_pad(GemmArgs g) {
  constexpr int LDT = 72;
  __shared__ unsigned short As[128 * LDT];
  __shared__ unsigned short Bs[128 * LDT];

  const int z = blockIdx.z;
  const int q = z / g.divz, r = z % g.divz;
  const long long offA = q * g.sA1 + r * g.sA2;
  const long long offB = q * g.sB1 + r * g.sB2;
  const long long offC = q * g.sC1 + r * g.sC2;
  const int bn = blockIdx.x * 128;
  const int bm = blockIdx.y * 128;
  const int tid = threadIdx.x;
  const int lane = tid & 63;
  const int wave = tid >> 6;
  const int wr = (wave >> 1) * 64, wc = (wave & 1) * 64;
  const int l15 = lane & 15, l4 = lane >> 4;

  const f32x4 fz = {0.f, 0.f, 0.f, 0.f};
  f32x4 acc[4][4];
  #pragma unroll
  for (int i = 0; i < 4; ++i)
    #pragma unroll
    for (int j = 0; j < 4; ++j) acc[i][j] = fz;

  const int srow = tid >> 3;
  const int scg = (tid & 7) * 8;

  for (int kt = 0; kt < g.K; kt += 64) {
    __syncthreads();
    #pragma unroll
    for (int s = 0; s < 4; ++s) {
      const int row = s * 32 + srow;
      bf16x8 av = *(const bf16x8*)((const unsigned short*)g.A + offA +
                                   (long long)(bm + row) * g.lda + kt + scg);
      *(bf16x8*)&As[row * LDT + scg] = av;
      bf16x8 bv = {0, 0, 0, 0, 0, 0, 0, 0};
      if (bn + row < g.N)
        bv = *(const bf16x8*)(g.BT + offB + (long long)(bn + row) * g.ldbt + kt + scg);
      *(bf16x8*)&Bs[row * LDT + scg] = bv;
    }
    __syncthreads();

    #pragma unroll
    for (int ks = 0; ks < 64; ks += 32) {
      const int kk = ks + l4 * 8;
      bf16x8 af[4], bfv[4];
      #pragma unroll
      for (int i = 0; i < 4; ++i) {
        af[i]  = *(const bf16x8*)&As[(wr + i * 16 + l15) * LDT + kk];
        bfv[i] = *(const bf16x8*)&Bs[(wc + i * 16 + l15) * LDT + kk];
      }
      #pragma unroll
      for (int mi = 0; mi < 4; ++mi)
        #pragma unroll
        for (int ni = 0; ni < 4; ++ni)
          acc[mi][ni] =
              __builtin_amdgcn_mfma_f32_16x16x32_bf16(af[mi], bfv[ni], acc[mi][ni], 0, 0, 0);
    }
  }

  #pragma unroll
  for (int mi = 0; mi < 4; ++mi) {
    #pragma unroll
    for (int ni = 0; ni < 4; ++ni) {
      #pragma unroll
      for (int i = 0; i < 4; ++i) {
        const int row = bm + wr + mi * 16 + l4 * 4 + i;
        const int col = bn + wc + ni * 16 + l15;
        if (row < g.M && col < g.N) {
          float v = acc[mi][ni][i];
          if (BIAS) v += g.bias[col];
          if (OUT_F32)
            ((float*)g.C)[offC + (long long)row * g.ldc + col] = v;
          else
            ((unsigned short*)g.C)[offC + (long long)row * g.ldc + col] = f2bf(v);
        }
      }
    }
  }
}

// ---------------- K^T V per head (VALU) ------------------------------------
__global__ __launch_bounds__(256) void ktv_kernel(const unsigned short* __restrict__ QKV,
                                                  unsigned short* __restrict__ Mh) {
  const int z = blockIdx.x;  // b*12 + h
  const int b = z / 12, h = z % 12;
  __shared__ unsigned short Ks[32 * 64];
  __shared__ unsigned short Vs[32 * 64];
  const int tid = threadIdx.x;
  const int ti = tid & 15, tj = tid >> 4;
  const int srow = tid >> 3, scg = (tid & 7) * 8;

  float acc[4][4];
  #pragma unroll
  for (int i = 0; i < 4; ++i)
    #pragma unroll
    for (int j = 0; j < 4; ++j) acc[i][j] = 0.f;

  const long long baseK = (long long)b * 1024 * 2304 + 768 + h * 64;
  for (int tc = 0; tc < 1024; tc += 32) {
    __syncthreads();
    const long long gidx = baseK + (long long)(tc + srow) * 2304 + scg;
    *(bf16x8*)&Ks[srow * 64 + scg] = *(const bf16x8*)&QKV[gidx];
    *(bf16x8*)&Vs[srow * 64 + scg] = *(const bf16x8*)&QKV[gidx + 768];
    __syncthreads();
    #pragma unroll 8
    for (int t = 0; t < 32; ++t) {
      const short4v ka = *(const short4v*)&Ks[t * 64 + ti * 4];
      const short4v va = *(const short4v*)&Vs[t * 64 + tj * 4];
      float a0 = bf2f((unsigned short)ka[0]), a1 = bf2f((unsigned short)ka[1]);
      float a2 = bf2f((unsigned short)ka[2]), a3 = bf2f((unsigned short)ka[3]);
      float b0 = bf2f((unsigned short)va[0]), b1 = bf2f((unsigned short)va[1]);
      float b2 = bf2f((unsigned short)va[2]), b3 = bf2f((unsigned short)va[3]);
      acc[0][0] += a0 * b0; acc[0][1] += a0 * b1; acc[0][2] += a0 * b2; acc[0][3] += a0 * b3;
      acc[1][0] += a1 * b0; acc[1][1] += a1 * b1; acc[1][2] += a1 * b2; acc[1][3] += a1 * b3;
      acc[2][0] += a2 * b0; acc[2][1] += a2 * b1; acc[2][2] += a2 * b2; acc[2][3] += a2 * b3;
      acc[3][0] += a3 * b0; acc[3][1] += a3 * b1; acc[3][2] += a3 * b2; acc[3][3] += a3 * b3;
    }
  }
  const long long mb = (long long)z * 4096;
  #pragma unroll
  for (int i = 0; i < 4; ++i) {
    short4v mv;
    #pragma unroll
    for (int j = 0; j < 4; ++j) mv[j] = (short)f2bf(acc[i][j]);
    *(short4v*)&Mh[mb + (ti * 4 + i) * 64 + tj * 4] = mv;
  }
}

// ---------------------------------------------------------------------------
extern "C" void kernel_launch(void* const* d_in, const int* in_sizes, int n_in,
                              void* d_out, int out_size, void* d_ws, size_t ws_size,
                              hipStream_t stream) {
  (void)in_sizes; (void)n_in; (void)out_size; (void)ws_size;
  const float* x    = (const float*)d_in[0];  // [16384,768]
  const float* Wqkv = (const float*)d_in[1];  // [768,2304]
  const float* bqkv = (const float*)d_in[2];  // [2304]
  const float* Wout = (const float*)d_in[3];  // [768,768]
  const float* bout = (const float*)d_in[4];  // [768]
  float* out = (float*)d_out;                 // [16384,768] f32

  char* ws = (char*)d_ws;
  size_t off = 0;
  auto carve = [&](size_t bytes) {
    char* p = ws + off;
    off += (bytes + 255) & ~(size_t)255;
    return p;
  };
  unsigned short* WqkvT = (unsigned short*)carve((size_t)2304 * 768 * 2);    // 3.5 MB
  unsigned short* WoutT = (unsigned short*)carve((size_t)768 * 768 * 2);     // 1.2 MB
  unsigned short* QKV   = (unsigned short*)carve((size_t)16384 * 2304 * 2);  // 72.5 MB
  unsigned short* Mh    = (unsigned short*)carve((size_t)192 * 64 * 64 * 2); // 1.6 MB
  unsigned short* xbf   = (unsigned short*)carve((size_t)16384 * 768 * 2);   // 25.2 MB
  // W2T aliases xbf: xbf is dead after gemm1; W2T (18 MB) fits inside it.
  unsigned short* W2T   = xbf;
  // total ~104 MB of d_ws

  // 0) x -> bf16
  cvt_f32_bf16<<<dim3(16384 * 768 / 8 / 256), 256, 0, stream>>>(x, xbf);
  // weights -> bf16 transposed
  transpose_cvt<<<dim3(2304 / 32, 768 / 32), 256, 0, stream>>>(Wqkv, WqkvT, 768, 2304);
  transpose_cvt<<<dim3(768 / 32, 768 / 32), 256, 0, stream>>>(Wout, WoutT, 768, 768);

  // 1) QKV = xbf @ Wqkv + b_qkv
  GemmArgs g1{};
  g1.A = xbf; g1.BT = WqkvT; g1.C = QKV; g1.bias = bqkv;
  g1.M = 16384; g1.N = 2304; g1.K = 768;
  g1.lda = 768; g1.ldbt = 768; g1.ldc = 2304;
  g1.divz = 1;
  gemm_lds<false, true><<<dim3(18, 128, 1), 256, 0, stream>>>(g1);

  // 2) M_h = K^T V per (b,h)
  ktv_kernel<<<dim3(192), 256, 0, stream>>>(QKV, Mh);

  // 3) W2T[b][j][h*64+d] = sum_e WoutT[j][h*64+e] * Mh[(b,h)][d][e]
  GemmArgs g2{};
  g2.A = WoutT; g2.BT = Mh; g2.C = W2T; g2.bias = nullptr;
  g2.M = 768; g2.N = 64; g2.K = 64;
  g2.lda = 768; g2.ldbt = 64; g2.ldc = 768;
  g2.divz = 12;
  g2.sA1 = 0;          g2.sA2 = 64;
  g2.sB1 = 12 * 4096;  g2.sB2 = 4096;
  g2.sC1 = 589824;     g2.sC2 = 64;
  gemm_pad<false, false><<<dim3(1, 6, 192), 256, 0, stream>>>(g2);

  // 4) out[b] = Q[b] @ W2[b] + b_out  (f32 out)
  GemmArgs g3{};
  g3.A = QKV; g3.BT = W2T; g3.C = out; g3.bias = bout;
  g3.M = 1024; g3.N = 768; g3.K = 768;
  g3.lda = 2304; g3.ldbt = 768; g3.ldc = 768;
  g3.divz = 1;
  g3.sA1 = 2359296;
  g3.sB1 = 589824;
  g3.sC1 = 786432;
  gemm_lds<true, true><<<dim3(6, 8, 16), 256, 0, stream>>>(g3);
}

// Round 3
// 185.144 us; speedup vs baseline: 1.4129x; 1.3218x over previous
//
#include <hip/hip_runtime.h>
#include <hip/hip_bf16.h>

// attentionHead: out = ((x@Wqkv+b) -> Q,K,V; (QK^T)V ; @Wout + b_out)
// No softmax => (QK^T)V = Q(K^T V). Per-head M_h = K^T V is 64x64.
// out = Q_cat @ (blockdiag(M_h) @ Wout) + b_out, Q_cat = QKV[:, :768].
//
// Pipeline:
//  0. cvt:           xbf  = bf16(x)
//  1. transpose_cvt: WqkvT, WoutT
//  2. gemm8p:        QKV = xbf @ Wqkv + b_qkv        (256^2 8-phase template)
//  3. ktv_part/red:  M_h = K^T V per (b,h), 4-way t-split
//  4. gemm_pad:      W2T[b] = blockdiag(Mh) @ Wout (transposed)
//  5. gemm8p:        out = Q @ W2[b] + b_out  (f32)

typedef __attribute__((ext_vector_type(8))) short bf16x8;
typedef __attribute__((ext_vector_type(4))) short short4v;
typedef __attribute__((ext_vector_type(4))) float f32x4;
typedef __attribute__((ext_vector_type(4))) float float4v;

typedef __attribute__((address_space(1))) const unsigned char ga_u8;
typedef __attribute__((address_space(3))) unsigned char la_u8;

__device__ __forceinline__ unsigned short f2bf(float f) {
  union { float f; unsigned int u; } v; v.f = f;
  unsigned int u = v.u;
  return (unsigned short)((u + 0x7FFFu + ((u >> 16) & 1u)) >> 16);  // RNE
}
__device__ __forceinline__ float bf2f(unsigned short s) {
  union { unsigned int u; float f; } v; v.u = ((unsigned int)s) << 16;
  return v.f;
}

// ---------------- f32 -> bf16 bulk convert ---------------------------------
__global__ __launch_bounds__(256) void cvt_f32_bf16(const float* __restrict__ in,
                                                    unsigned short* __restrict__ out) {
  const long long i = (long long)(blockIdx.x * 256 + threadIdx.x) * 8;
  float4v v0 = *(const float4v*)(in + i);
  float4v v1 = *(const float4v*)(in + i + 4);
  bf16x8 o;
  o[0] = (short)f2bf(v0[0]); o[1] = (short)f2bf(v0[1]);
  o[2] = (short)f2bf(v0[2]); o[3] = (short)f2bf(v0[3]);
  o[4] = (short)f2bf(v1[0]); o[5] = (short)f2bf(v1[1]);
  o[6] = (short)f2bf(v1[2]); o[7] = (short)f2bf(v1[3]);
  *(bf16x8*)(out + i) = o;
}

// ---------------- transpose + convert f32 -> bf16 --------------------------
__global__ __launch_bounds__(256) void transpose_cvt(const float* __restrict__ in,
                                                     unsigned short* __restrict__ out,
                                                     int R, int C) {
  __shared__ unsigned short tile[32][33];
  const int bx = blockIdx.x * 32;
  const int by = blockIdx.y * 32;
  const int tx = threadIdx.x & 31, ty = threadIdx.x >> 5;
  #pragma unroll
  for (int i = 0; i < 32; i += 8)
    tile[ty + i][tx] = f2bf(in[(long long)(by + ty + i) * C + bx + tx]);
  __syncthreads();
  #pragma unroll
  for (int i = 0; i < 32; i += 8)
    out[(long long)(bx + ty + i) * R + by + tx] = tile[tx][ty + i];
}

// ---------------- shared GEMM args -----------------------------------------
struct GemmArgs {
  const void* A;
  const unsigned short* BT;
  void* C;
  const float* bias;
  int M, N, K;
  int lda, ldbt, ldc;
  int divz;
  long long sA1, sA2, sB1, sB2, sC1, sC2;
};

// ---------------- 256x256 8-phase GEMM (m201 template, plain HIP) ----------
// D[m][n] = sum_k A[m][k]*BT[n][k] (+bias). Requires M%256==0, N%256==0,
// K%128==0, lda/ldbt%8==0, (gx*gy*gz)%8==0.
// LDS 128 KiB: [buf][A:0/B:16384][half*8192] shorts, each half 128x64 bf16.
// st_16x32 swizzle: k ^= ((row>>2)&1)<<4, applied on SOURCE and READ.

__device__ __forceinline__ bf16x8 ldsv(const unsigned short* b, int r, int k) {
  return *(const bf16x8*)&b[r * 64 + (k ^ (((r >> 2) & 1) << 4))];
}

#define LOADB(Bs_)                                                    \
  _Pragma("unroll")                                                   \
  for (int nf = 0; nf < 4; ++nf) {                                    \
    bfr[nf][0] = ldsv(Bs_, brow + nf * 16, l4 * 8);                   \
    bfr[nf][1] = ldsv(Bs_, brow + nf * 16, 32 + l4 * 8);              \
  }

#define PH(bufc, mq, first, STAGE_CALL)                                          \
  {                                                                              \
    const unsigned short* As_ = &L[(bufc) * 32768 + wm * 8192];                  \
    const unsigned short* Bs_ = &L[(bufc) * 32768 + 16384 + bhalf * 8192];       \
    if (first) { LOADB(Bs_) }                                                    \
    bf16x8 af0k0 = ldsv(As_, ((mq) * 2 + 0) * 16 + l15, l4 * 8);                 \
    bf16x8 af0k1 = ldsv(As_, ((mq) * 2 + 0) * 16 + l15, 32 + l4 * 8);            \
    bf16x8 af1k0 = ldsv(As_, ((mq) * 2 + 1) * 16 + l15, l4 * 8);                 \
    bf16x8 af1k1 = ldsv(As_, ((mq) * 2 + 1) * 16 + l15, 32 + l4 * 8);            \
    STAGE_CALL;                                                                  \
    if (first) asm volatile("s_waitcnt lgkmcnt(8)" ::: "memory");                \
    __builtin_amdgcn_s_barrier();                                                \
    asm volatile("s_waitcnt lgkmcnt(0)" ::: "memory");                           \
    __builtin_amdgcn_s_setprio(1);                                               \
    _Pragma("unroll")                                                            \
    for (int nf = 0; nf < 4; ++nf) {                                             \
      acc[(mq) * 2 + 0][nf] = __builtin_amdgcn_mfma_f32_16x16x32_bf16(           \
          af0k0, bfr[nf][0], acc[(mq) * 2 + 0][nf], 0, 0, 0);                    \
      acc[(mq) * 2 + 0][nf] = __builtin_amdgcn_mfma_f32_16x16x32_bf16(           \
          af0k1, bfr[nf][1], acc[(mq) * 2 + 0][nf], 0, 0, 0);                    \
      acc[(mq) * 2 + 1][nf] = __builtin_amdgcn_mfma_f32_16x16x32_bf16(           \
          af1k0, bfr[nf][0], acc[(mq) * 2 + 1][nf], 0, 0, 0);                    \
      acc[(mq) * 2 + 1][nf] = __builtin_amdgcn_mfma_f32_16x16x32_bf16(           \
          af1k1, bfr[nf][1], acc[(mq) * 2 + 1][nf], 0, 0, 0);                    \
    }                                                                            \
    __builtin_amdgcn_s_setprio(0);                                               \
  }

#define TB  { __builtin_amdgcn_s_barrier(); asm volatile("" ::: "memory"); }
#define TBV { asm volatile("s_waitcnt vmcnt(4)" ::: "memory");                   \
              __builtin_amdgcn_s_barrier(); asm volatile("" ::: "memory"); }

template <bool OUT_F32, bool BIAS>
__global__ __launch_bounds__(512, 2) void gemm8p(GemmArgs g) {
  __shared__ unsigned short L[65536];  // 128 KiB

  // bijective XCD swizzle over flattened (x,y,z); requires nwg%8==0
  const int gx = gridDim.x, gy = gridDim.y;
  const int nwg = gx * gy * gridDim.z;
  int flat = (blockIdx.z * gy + blockIdx.y) * gx + blockIdx.x;
  flat = (flat & 7) * (nwg >> 3) + (flat >> 3);
  const int gxy = gx * gy;
  const int bz = flat / gxy;
  const int rem = flat - bz * gxy;
  const int by = rem / gx;
  const int bx = rem - by * gx;

  const int q = bz / g.divz, r = bz % g.divz;
  const long long offA = q * g.sA1 + r * g.sA2;
  const long long offB = q * g.sB1 + r * g.sB2;
  const long long offC = q * g.sC1 + r * g.sC2;
  const int bm = by * 256, bn = bx * 256;

  const int tid = threadIdx.x;
  const int lane = tid & 63, wave = tid >> 6;
  const int wm = wave >> 2, wn = wave & 3;      // 2 x 4 waves
  const int l15 = lane & 15, l4 = lane >> 4;
  const int bhalf = wn >> 1;
  const int brow = (wn & 1) * 64 + l15;

  const unsigned short* Ab = (const unsigned short*)g.A + offA + (long long)bm * g.lda;
  const unsigned short* Bb = g.BT + offB + (long long)bn * g.ldbt;
  const int NT = g.K >> 6;  // even

  // stage one 128x64 half-tile: 2 x global_load_lds(16B) per thread,
  // linear LDS dest + pre-swizzled global source.
  auto stg = [&](int bufsel, int isB, int half, int t) {
    const int kts = (t < NT ? t : 0) << 6;
    const long long ld = isB ? g.ldbt : g.lda;
    const unsigned short* src = (isB ? Bb : Ab) + (long long)(half * 128) * ld + kts;
    unsigned short* dst = &L[bufsel * 32768 + isB * 16384 + half * 8192];
    #pragma unroll
    for (int rnd = 0; rnd < 2; ++rnd) {
      const int c = rnd * 512 + tid;
      const int row = c >> 3;
      const int kl = (c & 7) << 3;
      const int ksz = kl ^ (((row >> 2) & 1) << 4);
      __builtin_amdgcn_global_load_lds((ga_u8*)(src + (long long)row * ld + ksz),
                                       (la_u8*)(dst + c * 8), 16, 0, 0);
    }
  };

  const f32x4 fz = {0.f, 0.f, 0.f, 0.f};
  f32x4 acc[8][4];
  #pragma unroll
  for (int i = 0; i < 8; ++i)
    #pragma unroll
    for (int j = 0; j < 4; ++j) acc[i][j] = fz;
  bf16x8 bfr[4][2];

  // prologue: buf0 full tile0, buf1.B tile1 -> 12 loads; wait buf0 (leave 4)
  stg(0, 0, 0, 0); stg(0, 0, 1, 0); stg(0, 1, 0, 0); stg(0, 1, 1, 0);
  stg(1, 1, 0, 1); stg(1, 1, 1, 1);
  asm volatile("s_waitcnt vmcnt(4)" ::: "memory");
  __builtin_amdgcn_s_barrier();
  asm volatile("" ::: "memory");

  const int nt2 = NT >> 1;
  for (int i = 0; i < nt2; ++i) {
    const int tB = 2 * i + 1;
    // K-tile 2i from buf0
    PH(0, 0, true,  stg(1, 0, 0, tB))       TB
    PH(0, 1, false, stg(1, 0, 1, tB))       TB
    PH(0, 2, false, stg(0, 1, 0, tB + 1))   TB
    PH(0, 3, false, stg(0, 1, 1, tB + 1))   TBV
    // K-tile 2i+1 from buf1
    PH(1, 0, true,  stg(0, 0, 0, tB + 1))   TB
    PH(1, 1, false, stg(0, 0, 1, tB + 1))   TB
    PH(1, 2, false, stg(1, 1, 0, tB + 2))   TB
    PH(1, 3, false, stg(1, 1, 1, tB + 2))   TBV
  }

  // epilogue: C/D layout col=lane&15, row=(lane>>4)*4+ii
  #pragma unroll
  for (int mf = 0; mf < 8; ++mf) {
    #pragma unroll
    for (int nf = 0; nf < 4; ++nf) {
      #pragma unroll
      for (int ii = 0; ii < 4; ++ii) {
        const int row = bm + wm * 128 + mf * 16 + l4 * 4 + ii;
        const int col = bn + wn * 64 + nf * 16 + l15;
        float v = acc[mf][nf][ii];
        if (BIAS) v += g.bias[col];
        if (OUT_F32)
          ((float*)g.C)[offC + (long long)row * g.ldc + col] = v;
        else
          ((unsigned short*)g.C)[offC + (long long)row * g.ldc + col] = f2bf(v);
      }
    }
  }
}

// ---------------- padded reg-staging GEMM (small/guarded shapes) -----------
template <bool OUT_F32, bool BIAS>
__global__ __launch_bounds__(256) void gemm_pad(GemmArgs g) {
  constexpr int LDT = 72;
  __shared__ unsigned short As[128 * LDT];
  __shared__ unsigned short Bs[128 * LDT];

  const int z = blockIdx.z;
  const int q = z / g.divz, r = z % g.divz;
  const long long offA = q * g.sA1 + r * g.sA2;
  const long long offB = q * g.sB1 + r * g.sB2;
  const long long offC = q * g.sC1 + r * g.sC2;
  const int bn = blockIdx.x * 128;
  const int bm = blockIdx.y * 128;
  const int tid = threadIdx.x;
  const int lane = tid & 63;
  const int wave = tid >> 6;
  const int wr = (wave >> 1) * 64, wc = (wave & 1) * 64;
  const int l15 = lane & 15, l4 = lane >> 4;

  const f32x4 fz = {0.f, 0.f, 0.f, 0.f};
  f32x4 acc[4][4];
  #pragma unroll
  for (int i = 0; i < 4; ++i)
    #pragma unroll
    for (int j = 0; j < 4; ++j) acc[i][j] = fz;

  const int srow = tid >> 3;
  const int scg = (tid & 7) * 8;

  for (int kt = 0; kt < g.K; kt += 64) {
    __syncthreads();
    #pragma unroll
    for (int s = 0; s < 4; ++s) {
      const int row = s * 32 + srow;
      bf16x8 av = *(const bf16x8*)((const unsigned short*)g.A + offA +
                                   (long long)(bm + row) * g.lda + kt + scg);
      *(bf16x8*)&As[row * LDT + scg] = av;
      bf16x8 bv = {0, 0, 0, 0, 0, 0, 0, 0};
      if (bn + row < g.N)
        bv = *(const bf16x8*)(g.BT + offB + (long long)(bn + row) * g.ldbt + kt + scg);
      *(bf16x8*)&Bs[row * LDT + scg] = bv;
    }
    __syncthreads();

    #pragma unroll
    for (int ks = 0; ks < 64; ks += 32) {
      const int kk = ks + l4 * 8;
      bf16x8 af[4], bfv[4];
      #pragma unroll
      for (int i = 0; i < 4; ++i) {
        af[i]  = *(const bf16x8*)&As[(wr + i * 16 + l15) * LDT + kk];
        bfv[i] = *(const bf16x8*)&Bs[(wc + i * 16 + l15) * LDT + kk];
      }
      #pragma unroll
      for (int mi = 0; mi < 4; ++mi)
        #pragma unroll
        for (int ni = 0; ni < 4; ++ni)
          acc[mi][ni] =
              __builtin_amdgcn_mfma_f32_16x16x32_bf16(af[mi], bfv[ni], acc[mi][ni], 0, 0, 0);
    }
  }

  #pragma unroll
  for (int mi = 0; mi < 4; ++mi) {
    #pragma unroll
    for (int ni = 0; ni < 4; ++ni) {
      #pragma unroll
      for (int i = 0; i < 4; ++i) {
        const int row = bm + wr + mi * 16 + l4 * 4 + i;
        const int col = bn + wc + ni * 16 + l15;
        if (row < g.M && col < g.N) {
          float v = acc[mi][ni][i];
          if (BIAS) v += g.bias[col];
          if (OUT_F32)
            ((float*)g.C)[offC + (long long)row * g.ldc + col] = v;
          else
            ((unsigned short*)g.C)[offC + (long long)row * g.ldc + col] = f2bf(v);
        }
      }
    }
  }
}

// ---------------- K^T V per head, 4-way t-split + reduce -------------------
__global__ __launch_bounds__(256) void ktv_part(const unsigned short* __restrict__ QKV,
                                                float* __restrict__ Mp) {
  const int z = blockIdx.x;        // (b*12+h)*4 + chunk
  const int bh = z >> 2, chunk = z & 3;
  const int b = bh / 12, h = bh % 12;
  __shared__ unsigned short Ks[32 * 64];
  __shared__ unsigned short Vs[32 * 64];
  const int tid = threadIdx.x;
  const int ti = tid & 15, tj = tid >> 4;
  const int srow = tid >> 3, scg = (tid & 7) * 8;

  float acc[4][4];
  #pragma unroll
  for (int i = 0; i < 4; ++i)
    #pragma unroll
    for (int j = 0; j < 4; ++j) acc[i][j] = 0.f;

  const long long baseK = (long long)b * 1024 * 2304 + 768 + h * 64;
  const int t0 = chunk * 256;
  for (int tc = t0; tc < t0 + 256; tc += 32) {
    __syncthreads();
    const long long gidx = baseK + (long long)(tc + srow) * 2304 + scg;
    *(bf16x8*)&Ks[srow * 64 + scg] = *(const bf16x8*)&QKV[gidx];
    *(bf16x8*)&Vs[srow * 64 + scg] = *(const bf16x8*)&QKV[gidx + 768];
    __syncthreads();
    #pragma unroll 8
    for (int t = 0; t < 32; ++t) {
      const short4v ka = *(const short4v*)&Ks[t * 64 + ti * 4];
      const short4v va = *(const short4v*)&Vs[t * 64 + tj * 4];
      float a0 = bf2f((unsigned short)ka[0]), a1 = bf2f((unsigned short)ka[1]);
      float a2 = bf2f((unsigned short)ka[2]), a3 = bf2f((unsigned short)ka[3]);
      float b0 = bf2f((unsigned short)va[0]), b1 = bf2f((unsigned short)va[1]);
      float b2 = bf2f((unsigned short)va[2]), b3 = bf2f((unsigned short)va[3]);
      acc[0][0] += a0 * b0; acc[0][1] += a0 * b1; acc[0][2] += a0 * b2; acc[0][3] += a0 * b3;
      acc[1][0] += a1 * b0; acc[1][1] += a1 * b1; acc[1][2] += a1 * b2; acc[1][3] += a1 * b3;
      acc[2][0] += a2 * b0; acc[2][1] += a2 * b1; acc[2][2] += a2 * b2; acc[2][3] += a2 * b3;
      acc[3][0] += a3 * b0; acc[3][1] += a3 * b1; acc[3][2] += a3 * b2; acc[3][3] += a3 * b3;
    }
  }
  float* mp = Mp + (long long)z * 4096;
  #pragma unroll
  for (int i = 0; i < 4; ++i) {
    float4v v = {acc[i][0], acc[i][1], acc[i][2], acc[i][3]};
    *(float4v*)&mp[(ti * 4 + i) * 64 + tj * 4] = v;
  }
}

__global__ __launch_bounds__(256) void ktv_reduce(const float* __restrict__ Mp,
                                                  unsigned short* __restrict__ Mh) {
  const int idx = blockIdx.x * 256 + threadIdx.x;  // 192*1024 threads
  const int bh = idx >> 10;
  const int e4 = (idx & 1023) * 4;
  const float* p = Mp + (long long)bh * 16384 + e4;
  float4v s = *(const float4v*)p;
  #pragma unroll
  for (int c = 1; c < 4; ++c) {
    float4v v = *(const float4v*)(p + c * 4096);
    s[0] += v[0]; s[1] += v[1]; s[2] += v[2]; s[3] += v[3];
  }
  short4v o;
  #pragma unroll
  for (int j = 0; j < 4; ++j) o[j] = (short)f2bf(s[j]);
  *(short4v*)&Mh[(long long)bh * 4096 + e4] = o;
}

// ---------------------------------------------------------------------------
extern "C" void kernel_launch(void* const* d_in, const int* in_sizes, int n_in,
                              void* d_out, int out_size, void* d_ws, size_t ws_size,
                              hipStream_t stream) {
  (void)in_sizes; (void)n_in; (void)out_size; (void)ws_size;
  const float* x    = (const float*)d_in[0];  // [16384,768]
  const float* Wqkv = (const float*)d_in[1];  // [768,2304]
  const float* bqkv = (const float*)d_in[2];  // [2304]
  const float* Wout = (const float*)d_in[3];  // [768,768]
  const float* bout = (const float*)d_in[4];  // [768]
  float* out = (float*)d_out;                 // [16384,768] f32

  char* ws = (char*)d_ws;
  size_t off = 0;
  auto carve = [&](size_t bytes) {
    char* p = ws + off;
    off += (bytes + 255) & ~(size_t)255;
    return p;
  };
  unsigned short* WqkvT = (unsigned short*)carve((size_t)2304 * 768 * 2);    // 3.5 MB
  unsigned short* WoutT = (unsigned short*)carve((size_t)768 * 768 * 2);     // 1.2 MB
  unsigned short* QKV   = (unsigned short*)carve((size_t)16384 * 2304 * 2);  // 72.5 MB
  unsigned short* Mh    = (unsigned short*)carve((size_t)192 * 64 * 64 * 2); // 1.6 MB
  float*          Mp    = (float*)carve((size_t)768 * 4096 * 4);             // 12.6 MB
  unsigned short* xbf   = (unsigned short*)carve((size_t)16384 * 768 * 2);   // 25.2 MB
  unsigned short* W2T   = xbf;  // aliases xbf (dead after gemm1); 18 MB fits
  // total ~116 MB of d_ws

  cvt_f32_bf16<<<dim3(16384 * 768 / 8 / 256), 256, 0, stream>>>(x, xbf);
  transpose_cvt<<<dim3(2304 / 32, 768 / 32), 256, 0, stream>>>(Wqkv, WqkvT, 768, 2304);
  transpose_cvt<<<dim3(768 / 32, 768 / 32), 256, 0, stream>>>(Wout, WoutT, 768, 768);

  // 1) QKV = xbf @ Wqkv + b_qkv   (grid 9*64=576, %8==0)
  GemmArgs g1{};
  g1.A = xbf; g1.BT = WqkvT; g1.C = QKV; g1.bias = bqkv;
  g1.M = 16384; g1.N = 2304; g1.K = 768;
  g1.lda = 768; g1.ldbt = 768; g1.ldc = 2304;
  g1.divz = 1;
  gemm8p<false, true><<<dim3(9, 64, 1), 512, 0, stream>>>(g1);

  // 2) M_h = K^T V per (b,h), split 4 ways over t
  ktv_part<<<dim3(768), 256, 0, stream>>>(QKV, Mp);
  ktv_reduce<<<dim3(768), 256, 0, stream>>>(Mp, Mh);

  // 3) W2T[b][j][h*64+d] = sum_e WoutT[j][h*64+e] * Mh[(b,h)][d][e]
  GemmArgs g2{};
  g2.A = WoutT; g2.BT = Mh; g2.C = W2T; g2.bias = nullptr;
  g2.M = 768; g2.N = 64; g2.K = 64;
  g2.lda = 768; g2.ldbt = 64; g2.ldc = 768;
  g2.divz = 12;
  g2.sA1 = 0;          g2.sA2 = 64;
  g2.sB1 = 12 * 4096;  g2.sB2 = 4096;
  g2.sC1 = 589824;     g2.sC2 = 64;
  gemm_pad<false, false><<<dim3(1, 6, 192), 256, 0, stream>>>(g2);

  // 4) out[b] = Q[b] @ W2[b] + b_out  (grid 3*4*16=192, %8==0)
  GemmArgs g3{};
  g3.A = QKV; g3.BT = W2T; g3.C = out; g3.bias = bout;
  g3.M = 1024; g3.N = 768; g3.K = 768;
  g3.lda = 2304; g3.ldbt = 768; g3.ldc = 768;
  g3.divz = 1;
  g3.sA1 = 2359296;
  g3.sB1 = 589824;
  g3.sC1 = 786432;
  gemm8p<true, true><<<dim3(3, 4, 16), 512, 0, stream>>>(g3);
}

// Round 4
// 162.757 us; speedup vs baseline: 1.6073x; 1.1375x over previous
//
#include <hip/hip_runtime.h>
#include <hip/hip_bf16.h>

// attentionHead: out = ((x@Wqkv+b) -> Q,K,V; (QK^T)V ; @Wout + b_out)
// No softmax => (QK^T)V = Q(K^T V). Per-head M_h = K^T V is 64x64.
// out = Q_cat @ (blockdiag(M_h) @ Wout) + b_out, Q_cat = QKV[:, :768].
//
// Pipeline:
//  0. cvt:           xbf  = bf16(x)
//  1. transpose_cvt: WqkvT, WoutT
//  2. gemm8p:        QKV = xbf @ Wqkv + b_qkv   (256x192 8-phase, rotation swizzle)
//  3. ktv_part/red:  M_h = K^T V per (b,h), 4-way t-split
//  4. gemm_w2t:      W2T[b][j][:] = blockdiag(Mh) @ Wout (transposed)
//  5. gemm8p:        out = Q @ W2[b] + b_out  (f32)

typedef __attribute__((ext_vector_type(8))) short bf16x8;
typedef __attribute__((ext_vector_type(4))) short short4v;
typedef __attribute__((ext_vector_type(4))) float f32x4;
typedef __attribute__((ext_vector_type(4))) float float4v;

typedef __attribute__((address_space(1))) const unsigned char ga_u8;
typedef __attribute__((address_space(3))) unsigned char la_u8;

__device__ __forceinline__ unsigned short f2bf(float f) {
  union { float f; unsigned int u; } v; v.f = f;
  unsigned int u = v.u;
  return (unsigned short)((u + 0x7FFFu + ((u >> 16) & 1u)) >> 16);  // RNE
}
__device__ __forceinline__ float bf2f(unsigned short s) {
  union { unsigned int u; float f; } v; v.u = ((unsigned int)s) << 16;
  return v.f;
}

// ---------------- f32 -> bf16 bulk convert ---------------------------------
__global__ __launch_bounds__(256) void cvt_f32_bf16(const float* __restrict__ in,
                                                    unsigned short* __restrict__ out) {
  const long long i = (long long)(blockIdx.x * 256 + threadIdx.x) * 8;
  float4v v0 = *(const float4v*)(in + i);
  float4v v1 = *(const float4v*)(in + i + 4);
  bf16x8 o;
  o[0] = (short)f2bf(v0[0]); o[1] = (short)f2bf(v0[1]);
  o[2] = (short)f2bf(v0[2]); o[3] = (short)f2bf(v0[3]);
  o[4] = (short)f2bf(v1[0]); o[5] = (short)f2bf(v1[1]);
  o[6] = (short)f2bf(v1[2]); o[7] = (short)f2bf(v1[3]);
  *(bf16x8*)(out + i) = o;
}

// ---------------- transpose + convert f32 -> bf16 --------------------------
__global__ __launch_bounds__(256) void transpose_cvt(const float* __restrict__ in,
                                                     unsigned short* __restrict__ out,
                                                     int R, int C) {
  __shared__ unsigned short tile[32][33];
  const int bx = blockIdx.x * 32;
  const int by = blockIdx.y * 32;
  const int tx = threadIdx.x & 31, ty = threadIdx.x >> 5;
  #pragma unroll
  for (int i = 0; i < 32; i += 8)
    tile[ty + i][tx] = f2bf(in[(long long)(by + ty + i) * C + bx + tx]);
  __syncthreads();
  #pragma unroll
  for (int i = 0; i < 32; i += 8)
    out[(long long)(bx + ty + i) * R + by + tx] = tile[tx][ty + i];
}

// ---------------- shared GEMM args -----------------------------------------
struct GemmArgs {
  const void* A;
  const unsigned short* BT;
  void* C;
  const float* bias;
  int M, N, K;
  int lda, ldbt, ldc;
  long long sA1, sB1, sC1;  // per-z offsets (elements)
};

// ---------------- 256x192 8-phase GEMM -------------------------------------
// D[m][n] = sum_k A[m][k]*BT[n][k] (+bias). Requires M%256==0, N%192==0,
// K%128==0, lda/ldbt%8==0, (gx*gy*gz)%8==0.
// LDS 112 KiB: A halves 128x64 at buf*16384 + half*8192 (shorts);
//              B halves  96x64 at 32768 + buf*12288 + half*6144.
// Rotation swizzle (both sides): LDS col' = (k + row*8)&63.

__device__ __forceinline__ bf16x8 ldsr(const unsigned short* b, int r, int k) {
  return *(const bf16x8*)&b[r * 64 + ((k + r * 8) & 63)];
}

#define MFMA_(a, b, c) __builtin_amdgcn_mfma_f32_16x16x32_bf16(a, b, c, 0, 0, 0)

#define PH(bufc, mq, first, STAGE_CALL)                                        \
  {                                                                            \
    const unsigned short* As_ = &L[(bufc) * 16384 + wm * 8192];                \
    const unsigned short* Bs_ = &L[32768 + (bufc) * 12288 + bhalf * 6144];     \
    if (first) {                                                               \
      _Pragma("unroll")                                                        \
      for (int nf = 0; nf < 3; ++nf) {                                         \
        bfr[nf][0] = ldsr(Bs_, brow + nf * 16, l4 * 8);                        \
        bfr[nf][1] = ldsr(Bs_, brow + nf * 16, 32 + l4 * 8);                   \
      }                                                                        \
    }                                                                          \
    bf16x8 af0k0 = ldsr(As_, ((mq) * 2 + 0) * 16 + l15, l4 * 8);               \
    bf16x8 af0k1 = ldsr(As_, ((mq) * 2 + 0) * 16 + l15, 32 + l4 * 8);          \
    bf16x8 af1k0 = ldsr(As_, ((mq) * 2 + 1) * 16 + l15, l4 * 8);               \
    bf16x8 af1k1 = ldsr(As_, ((mq) * 2 + 1) * 16 + l15, 32 + l4 * 8);          \
    STAGE_CALL;                                                                \
    if (first) asm volatile("s_waitcnt lgkmcnt(6)" ::: "memory");              \
    __builtin_amdgcn_s_barrier();                                              \
    asm volatile("s_waitcnt lgkmcnt(0)" ::: "memory");                         \
    __builtin_amdgcn_s_setprio(1);                                             \
    _Pragma("unroll")                                                          \
    for (int nf = 0; nf < 3; ++nf) {                                           \
      acc[(mq) * 2 + 0][nf] = MFMA_(af0k0, bfr[nf][0], acc[(mq) * 2 + 0][nf]); \
      acc[(mq) * 2 + 0][nf] = MFMA_(af0k1, bfr[nf][1], acc[(mq) * 2 + 0][nf]); \
      acc[(mq) * 2 + 1][nf] = MFMA_(af1k0, bfr[nf][0], acc[(mq) * 2 + 1][nf]); \
      acc[(mq) * 2 + 1][nf] = MFMA_(af1k1, bfr[nf][1], acc[(mq) * 2 + 1][nf]); \
    }                                                                          \
    __builtin_amdgcn_s_setprio(0);                                             \
  }

#define TB  { __builtin_amdgcn_s_barrier(); asm volatile("" ::: "memory"); }
#define TBV { asm volatile("s_waitcnt vmcnt(4)" ::: "memory");                 \
              __builtin_amdgcn_s_barrier(); asm volatile("" ::: "memory"); }

template <bool OUT_F32, bool BIAS>
__global__ __launch_bounds__(512, 2) void gemm8p(GemmArgs g) {
  __shared__ unsigned short L[57344];  // 112 KiB

  // bijective XCD swizzle over flattened (z,y,x); requires nwg%8==0
  const int gx = gridDim.x, gy = gridDim.y;
  const int nwg = gx * gy * gridDim.z;
  int flat = (blockIdx.z * gy + blockIdx.y) * gx + blockIdx.x;
  flat = (flat & 7) * (nwg >> 3) + (flat >> 3);
  const int gxy = gx * gy;
  const int bz = flat / gxy;
  const int rem = flat - bz * gxy;
  const int by = rem / gx;
  const int bx = rem - by * gx;

  const long long offA = bz * g.sA1;
  const long long offB = bz * g.sB1;
  const long long offC = bz * g.sC1;
  const int bm = by * 256, bn = bx * 192;

  const int tid = threadIdx.x;
  const int lane = tid & 63, wave = tid >> 6;
  const int wm = wave >> 2, wn = wave & 3;      // 2 x 4 waves; wave tile 128x48
  const int l15 = lane & 15, l4 = lane >> 4;
  const int bhalf = wn >> 1;
  const int brow = (wn & 1) * 48 + l15;

  const unsigned short* Ab = (const unsigned short*)g.A + offA + (long long)bm * g.lda;
  const unsigned short* Bb = g.BT + offB + (long long)bn * g.ldbt;
  const int NT = g.K >> 6;  // even

  // stage A half-tile (128x64): 2 x gload_lds(16B)/thread, rotation on source
  auto stgA = [&](int bufsel, int half, int t) {
    const int kts = (t < NT ? t : 0) << 6;
    const unsigned short* src = Ab + (long long)(half * 128) * g.lda + kts;
    unsigned short* dst = &L[bufsel * 16384 + half * 8192];
    #pragma unroll
    for (int rnd = 0; rnd < 2; ++rnd) {
      const int c = rnd * 512 + tid;          // 0..1023
      const int row = c >> 3, j = c & 7;
      const int srcj = (j - row) & 7;         // inverse rotation
      __builtin_amdgcn_global_load_lds((ga_u8*)(src + (long long)row * g.lda + srcj * 8),
                                       (la_u8*)(dst + c * 8), 16, 0, 0);
    }
  };
  // stage B half-tile (96x64): 768 chunks; uniform 2 instr/thread via
  // benign redundant reload of chunks 512..767 (same src -> same value).
  auto stgB = [&](int bufsel, int half, int t) {
    const int kts = (t < NT ? t : 0) << 6;
    const unsigned short* src = Bb + (long long)(half * 96) * g.ldbt + kts;
    unsigned short* dst = &L[32768 + bufsel * 12288 + half * 6144];
    #pragma unroll
    for (int rnd = 0; rnd < 2; ++rnd) {
      const int c0 = rnd * 512 + tid;
      const int c = (c0 >= 768) ? c0 - 256 : c0;
      const int row = c >> 3, j = c & 7;
      const int srcj = (j - row) & 7;
      __builtin_amdgcn_global_load_lds((ga_u8*)(src + (long long)row * g.ldbt + srcj * 8),
                                       (la_u8*)(dst + c * 8), 16, 0, 0);
    }
  };

  const f32x4 fz = {0.f, 0.f, 0.f, 0.f};
  f32x4 acc[8][3];
  #pragma unroll
  for (int i = 0; i < 8; ++i)
    #pragma unroll
    for (int j = 0; j < 3; ++j) acc[i][j] = fz;
  bf16x8 bfr[3][2];

  // prologue: tile0 A+B into buf0, tile1 B into buf1 -> 12 instr;
  // drain tile0 (8), leave B(1) (4) in flight.
  stgA(0, 0, 0); stgA(0, 1, 0); stgB(0, 0, 0); stgB(0, 1, 0);
  stgB(1, 0, 1); stgB(1, 1, 1);
  asm volatile("s_waitcnt vmcnt(4)" ::: "memory");
  __builtin_amdgcn_s_barrier();
  asm volatile("" ::: "memory");

  const int nt2 = NT >> 1;
  for (int i = 0; i < nt2; ++i) {
    const int t1 = 2 * i + 1;
    // K-tile 2i from buf0; stage A(2i+1)->buf1, B(2i+2)->buf0
    PH(0, 0, true,  stgA(1, 0, t1))      TB
    PH(0, 1, false, stgA(1, 1, t1))      TB
    PH(0, 2, false, stgB(0, 0, t1 + 1))  TB
    PH(0, 3, false, stgB(0, 1, t1 + 1))  TBV
    // K-tile 2i+1 from buf1; stage A(2i+2)->buf0, B(2i+3)->buf1
    PH(1, 0, true,  stgA(0, 0, t1 + 1))  TB
    PH(1, 1, false, stgA(0, 1, t1 + 1))  TB
    PH(1, 2, false, stgB(1, 0, t1 + 2))  TB
    PH(1, 3, false, stgB(1, 1, t1 + 2))  TBV
  }

  // epilogue: C/D layout col=lane&15, row=(lane>>4)*4+ii
  #pragma unroll
  for (int mf = 0; mf < 8; ++mf) {
    #pragma unroll
    for (int nf = 0; nf < 3; ++nf) {
      #pragma unroll
      for (int ii = 0; ii < 4; ++ii) {
        const int row = bm + wm * 128 + mf * 16 + l4 * 4 + ii;
        const int col = bn + wn * 48 + nf * 16 + l15;
        float v = acc[mf][nf][ii];
        if (BIAS) v += g.bias[col];
        if (OUT_F32)
          ((float*)g.C)[offC + (long long)row * g.ldc + col] = v;
        else
          ((unsigned short*)g.C)[offC + (long long)row * g.ldc + col] = f2bf(v);
      }
    }
  }
}

// ---------------- W2T: per-(b,h) 768x64x64 GEMM ----------------------------
// C[j][d] = sum_e WoutT[j][h*64+e] * Mh[(b,h)][d][e]; tile 128(M)x64(N), K=64.
__global__ __launch_bounds__(256) void gemm_w2t(const unsigned short* __restrict__ WoutT,
                                                const unsigned short* __restrict__ Mh,
                                                unsigned short* __restrict__ W2T) {
  constexpr int LDT = 72;
  __shared__ unsigned short As[128 * LDT];
  __shared__ unsigned short Bs[64 * LDT];

  const int bm = blockIdx.x * 128;       // j block (768/128 = 6)
  const int z = blockIdx.y;              // b*12 + h
  const int b = z / 12, h = z % 12;
  const int tid = threadIdx.x;
  const int lane = tid & 63, wave = tid >> 6;   // 4 waves x 32 rows
  const int l15 = lane & 15, l4 = lane >> 4;
  const int srow = tid >> 3, scg = (tid & 7) * 8;

  const unsigned short* Abase = WoutT + (long long)bm * 768 + h * 64;
  const unsigned short* Bbase = Mh + (long long)z * 4096;

  // stage
  #pragma unroll
  for (int s = 0; s < 4; ++s) {
    const int row = s * 32 + srow;
    *(bf16x8*)&As[row * LDT + scg] =
        *(const bf16x8*)(Abase + (long long)row * 768 + scg);
  }
  #pragma unroll
  for (int s = 0; s < 2; ++s) {
    const int row = s * 32 + srow;
    *(bf16x8*)&Bs[row * LDT + scg] = *(const bf16x8*)(Bbase + row * 64 + scg);
  }
  __syncthreads();

  const f32x4 fz = {0.f, 0.f, 0.f, 0.f};
  f32x4 acc[2][4];
  #pragma unroll
  for (int i = 0; i < 2; ++i)
    #pragma unroll
    for (int j = 0; j < 4; ++j) acc[i][j] = fz;

  #pragma unroll
  for (int ks = 0; ks < 64; ks += 32) {
    const int kk = ks + l4 * 8;
    bf16x8 af[2], bfv[4];
    #pragma unroll
    for (int i = 0; i < 2; ++i)
      af[i] = *(const bf16x8*)&As[(wave * 32 + i * 16 + l15) * LDT + kk];
    #pragma unroll
    for (int i = 0; i < 4; ++i)
      bfv[i] = *(const bf16x8*)&Bs[(i * 16 + l15) * LDT + kk];
    #pragma unroll
    for (int mi = 0; mi < 2; ++mi)
      #pragma unroll
      for (int ni = 0; ni < 4; ++ni)
        acc[mi][ni] = MFMA_(af[mi], bfv[ni], acc[mi][ni]);
  }

  unsigned short* Cb = W2T + (long long)b * 589824 + h * 64;
  #pragma unroll
  for (int mi = 0; mi < 2; ++mi)
    #pragma unroll
    for (int ni = 0; ni < 4; ++ni)
      #pragma unroll
      for (int ii = 0; ii < 4; ++ii) {
        const int row = bm + wave * 32 + mi * 16 + l4 * 4 + ii;
        const int col = ni * 16 + l15;
        Cb[(long long)row * 768 + col] = f2bf(acc[mi][ni][ii]);
      }
}

// ---------------- K^T V per head, 4-way t-split + reduce -------------------
__global__ __launch_bounds__(256) void ktv_part(const unsigned short* __restrict__ QKV,
                                                float* __restrict__ Mp) {
  const int z = blockIdx.x;        // (b*12+h)*4 + chunk
  const int bh = z >> 2, chunk = z & 3;
  const int b = bh / 12, h = bh % 12;
  __shared__ unsigned short Ks[32 * 64];
  __shared__ unsigned short Vs[32 * 64];
  const int tid = threadIdx.x;
  const int ti = tid & 15, tj = tid >> 4;
  const int srow = tid >> 3, scg = (tid & 7) * 8;

  float acc[4][4];
  #pragma unroll
  for (int i = 0; i < 4; ++i)
    #pragma unroll
    for (int j = 0; j < 4; ++j) acc[i][j] = 0.f;

  const long long baseK = (long long)b * 1024 * 2304 + 768 + h * 64;
  const int t0 = chunk * 256;
  for (int tc = t0; tc < t0 + 256; tc += 32) {
    __syncthreads();
    const long long gidx = baseK + (long long)(tc + srow) * 2304 + scg;
    *(bf16x8*)&Ks[srow * 64 + scg] = *(const bf16x8*)&QKV[gidx];
    *(bf16x8*)&Vs[srow * 64 + scg] = *(const bf16x8*)&QKV[gidx + 768];
    __syncthreads();
    #pragma unroll 8
    for (int t = 0; t < 32; ++t) {
      const short4v ka = *(const short4v*)&Ks[t * 64 + ti * 4];
      const short4v va = *(const short4v*)&Vs[t * 64 + tj * 4];
      float a0 = bf2f((unsigned short)ka[0]), a1 = bf2f((unsigned short)ka[1]);
      float a2 = bf2f((unsigned short)ka[2]), a3 = bf2f((unsigned short)ka[3]);
      float b0 = bf2f((unsigned short)va[0]), b1 = bf2f((unsigned short)va[1]);
      float b2 = bf2f((unsigned short)va[2]), b3 = bf2f((unsigned short)va[3]);
      acc[0][0] += a0 * b0; acc[0][1] += a0 * b1; acc[0][2] += a0 * b2; acc[0][3] += a0 * b3;
      acc[1][0] += a1 * b0; acc[1][1] += a1 * b1; acc[1][2] += a1 * b2; acc[1][3] += a1 * b3;
      acc[2][0] += a2 * b0; acc[2][1] += a2 * b1; acc[2][2] += a2 * b2; acc[2][3] += a2 * b3;
      acc[3][0] += a3 * b0; acc[3][1] += a3 * b1; acc[3][2] += a3 * b2; acc[3][3] += a3 * b3;
    }
  }
  float* mp = Mp + (long long)z * 4096;
  #pragma unroll
  for (int i = 0; i < 4; ++i) {
    float4v v = {acc[i][0], acc[i][1], acc[i][2], acc[i][3]};
    *(float4v*)&mp[(ti * 4 + i) * 64 + tj * 4] = v;
  }
}

__global__ __launch_bounds__(256) void ktv_reduce(const float* __restrict__ Mp,
                                                  unsigned short* __restrict__ Mh) {
  const int idx = blockIdx.x * 256 + threadIdx.x;
  const int bh = idx >> 10;
  const int e4 = (idx & 1023) * 4;
  const float* p = Mp + (long long)bh * 16384 + e4;
  float4v s = *(const float4v*)p;
  #pragma unroll
  for (int c = 1; c < 4; ++c) {
    float4v v = *(const float4v*)(p + c * 4096);
    s[0] += v[0]; s[1] += v[1]; s[2] += v[2]; s[3] += v[3];
  }
  short4v o;
  #pragma unroll
  for (int j = 0; j < 4; ++j) o[j] = (short)f2bf(s[j]);
  *(short4v*)&Mh[(long long)bh * 4096 + e4] = o;
}

// ---------------------------------------------------------------------------
extern "C" void kernel_launch(void* const* d_in, const int* in_sizes, int n_in,
                              void* d_out, int out_size, void* d_ws, size_t ws_size,
                              hipStream_t stream) {
  (void)in_sizes; (void)n_in; (void)out_size; (void)ws_size;
  const float* x    = (const float*)d_in[0];  // [16384,768]
  const float* Wqkv = (const float*)d_in[1];  // [768,2304]
  const float* bqkv = (const float*)d_in[2];  // [2304]
  const float* Wout = (const float*)d_in[3];  // [768,768]
  const float* bout = (const float*)d_in[4];  // [768]
  float* out = (float*)d_out;                 // [16384,768] f32

  char* ws = (char*)d_ws;
  size_t off = 0;
  auto carve = [&](size_t bytes) {
    char* p = ws + off;
    off += (bytes + 255) & ~(size_t)255;
    return p;
  };
  unsigned short* WqkvT = (unsigned short*)carve((size_t)2304 * 768 * 2);    // 3.5 MB
  unsigned short* WoutT = (unsigned short*)carve((size_t)768 * 768 * 2);     // 1.2 MB
  unsigned short* QKV   = (unsigned short*)carve((size_t)16384 * 2304 * 2);  // 72.5 MB
  unsigned short* Mh    = (unsigned short*)carve((size_t)192 * 64 * 64 * 2); // 1.6 MB
  float*          Mp    = (float*)carve((size_t)768 * 4096 * 4);             // 12.6 MB
  unsigned short* xbf   = (unsigned short*)carve((size_t)16384 * 768 * 2);   // 25.2 MB
  unsigned short* W2T   = xbf;  // aliases xbf (dead after gemm1); 18 MB fits
  // total ~116 MB of d_ws

  cvt_f32_bf16<<<dim3(16384 * 768 / 8 / 256), 256, 0, stream>>>(x, xbf);
  transpose_cvt<<<dim3(2304 / 32, 768 / 32), 256, 0, stream>>>(Wqkv, WqkvT, 768, 2304);
  transpose_cvt<<<dim3(768 / 32, 768 / 32), 256, 0, stream>>>(Wout, WoutT, 768, 768);

  // 1) QKV = xbf @ Wqkv + b_qkv   (grid 12*64=768 = 3 exact rounds)
  GemmArgs g1{};
  g1.A = xbf; g1.BT = WqkvT; g1.C = QKV; g1.bias = bqkv;
  g1.M = 16384; g1.N = 2304; g1.K = 768;
  g1.lda = 768; g1.ldbt = 768; g1.ldc = 2304;
  gemm8p<false, true><<<dim3(12, 64, 1), 512, 0, stream>>>(g1);

  // 2) M_h = K^T V per (b,h), split 4 ways over t
  ktv_part<<<dim3(768), 256, 0, stream>>>(QKV, Mp);
  ktv_reduce<<<dim3(768), 256, 0, stream>>>(Mp, Mh);

  // 3) W2T[b][j][h*64+d] = sum_e WoutT[j][h*64+e] * Mh[(b,h)][d][e]
  gemm_w2t<<<dim3(6, 192), 256, 0, stream>>>(WoutT, Mh, W2T);

  // 4) out[b] = Q[b] @ W2[b] + b_out  (grid 4*4*16=256 = 1 exact round)
  GemmArgs g3{};
  g3.A = QKV; g3.BT = W2T; g3.C = out; g3.bias = bout;
  g3.M = 1024; g3.N = 768; g3.K = 768;
  g3.lda = 2304; g3.ldbt = 768; g3.ldc = 768;
  g3.sA1 = 2359296;  // 1024*2304
  g3.sB1 = 589824;   // 768*768
  g3.sC1 = 786432;   // 1024*768
  gemm8p<true, true><<<dim3(4, 4, 16), 512, 0, stream>>>(g3);
}